// Round 4
// baseline (227.726 us; speedup 1.0000x reference)
//
#include <hip/hip_runtime.h>

#define HH 128

typedef __attribute__((ext_vector_type(8))) short bf16x8;
typedef __attribute__((ext_vector_type(4))) float f32x4;
typedef unsigned long long u64;

__device__ inline unsigned short f2bf(float f) {
    unsigned u = __builtin_bit_cast(unsigned, f);
    u += 0x7FFF + ((u >> 16) & 1);   // round to nearest even
    return (unsigned short)(u >> 16);
}

// ---------------- fused MFMA projection: both tables in one launch ----------------
__global__ __launch_bounds__(256) void project_both_kernel(
    const float* __restrict__ Zu, const float* __restrict__ Zi,
    const float* __restrict__ W1, const float* __restrict__ b1,
    unsigned short* __restrict__ Pu, unsigned short* __restrict__ Pi,
    int n_user, int n_item, int ublocks)
{
    __shared__ unsigned short sWt[128 * 128];    // 32 KB, chunk-XOR swizzled
    __shared__ unsigned short sOut[64 * 136];    // 17 KB

    const bool isUser = ((int)blockIdx.x < ublocks);
    const float* __restrict__ Z = isUser ? Zu : Zi;
    const float* __restrict__ W = isUser ? W1 : (W1 + HH * HH);
    unsigned short* __restrict__ P = isUser ? Pu : Pi;
    const int nrows  = isUser ? n_user : n_item;
    const int ntiles = (nrows + 63) >> 6;
    const int tbase  = (isUser ? (int)blockIdx.x : ((int)blockIdx.x - ublocks)) * 2;

    const int t    = threadIdx.x;
    const int wave = t >> 6;
    const int lane = t & 63;
    const int l16  = lane & 15;
    const int lk8  = (lane >> 4) * 8;

    #pragma unroll 4
    for (int i = 0; i < 16; ++i) {
        int idx = t + i * 256;
        int k   = idx >> 5;
        int c4  = (idx & 31) * 4;
        float4 w = *(const float4*)(W + (size_t)k * HH + c4);
        float wv[4] = {w.x, w.y, w.z, w.w};
        #pragma unroll
        for (int j = 0; j < 4; ++j) {
            int c = c4 + j;
            sWt[c * 128 + (((k >> 3) ^ (c & 15)) << 3) + (k & 7)] = f2bf(wv[j]);
        }
    }

    float b1r[8];
    #pragma unroll
    for (int nt = 0; nt < 8; ++nt)
        b1r[nt] = isUser ? b1[nt * 16 + l16] : 0.f;

    __syncthreads();

    #pragma unroll 1
    for (int s = 0; s < 2; ++s) {
        const int tile = tbase + s;
        if (tile >= ntiles) break;
        const int rbase = tile << 6;

        f32x4 acc[8];
        #pragma unroll
        for (int nt = 0; nt < 8; ++nt) acc[nt] = (f32x4)0.f;

        int m = rbase + wave * 16 + l16;
        if (m > nrows - 1) m = nrows - 1;
        const float* Zrow = Z + (size_t)m * HH;

        #pragma unroll
        for (int kk = 0; kk < 4; ++kk) {
            float4 z0 = *(const float4*)(Zrow + kk * 32 + lk8);
            float4 z1 = *(const float4*)(Zrow + kk * 32 + lk8 + 4);
            bf16x8 a;
            a[0] = (short)f2bf(z0.x); a[1] = (short)f2bf(z0.y);
            a[2] = (short)f2bf(z0.z); a[3] = (short)f2bf(z0.w);
            a[4] = (short)f2bf(z1.x); a[5] = (short)f2bf(z1.y);
            a[6] = (short)f2bf(z1.z); a[7] = (short)f2bf(z1.w);

            const int chunkSw = ((kk * 4 + (lane >> 4)) ^ l16) << 3;
            #pragma unroll
            for (int nt = 0; nt < 8; ++nt) {
                int c = nt * 16 + l16;
                bf16x8 b = *(const bf16x8*)(sWt + c * 128 + chunkSw);
                acc[nt] = __builtin_amdgcn_mfma_f32_16x16x32_bf16(a, b, acc[nt], 0, 0, 0);
            }
        }

        __syncthreads();
        #pragma unroll
        for (int nt = 0; nt < 8; ++nt) {
            int colc = nt * 16 + l16;
            #pragma unroll
            for (int r = 0; r < 4; ++r) {
                int orow = wave * 16 + (lane >> 4) * 4 + r;
                sOut[orow * 136 + colc] = f2bf(acc[nt][r] + b1r[nt]);
            }
        }
        __syncthreads();
        #pragma unroll
        for (int i = 0; i < 4; ++i) {
            int idx = t + i * 256;
            int r   = idx >> 4;
            int ch  = idx & 15;
            int grow = rbase + r;
            if (grow < nrows)
                *(uint4*)(P + (size_t)grow * HH + ch * 8) =
                    *(const uint4*)(sOut + r * 136 + ch * 8);
        }
    }
}

// ---------------- counting sort of edges by user ----------------
__global__ __launch_bounds__(256) void hist_kernel(
    const int* __restrict__ row, unsigned* __restrict__ hist, int E)
{
    int i  = blockIdx.x * blockDim.x + threadIdx.x;
    int st = gridDim.x * blockDim.x;
    for (int e = i; e < E; e += st) atomicAdd(&hist[row[e]], 1u);
}

// per-block exclusive scan over chunks of 2048; writes local scans into cursor, block sums into bsums
__global__ __launch_bounds__(256) void scan1_kernel(
    const unsigned* __restrict__ hist, unsigned* __restrict__ cursor,
    unsigned* __restrict__ bsums, int n)
{
    __shared__ unsigned s[256];
    const int t = threadIdx.x;
    const int start = blockIdx.x * 2048 + t * 8;
    unsigned v[8]; unsigned tsum = 0;
    #pragma unroll
    for (int j = 0; j < 8; ++j) {
        int idx = start + j;
        v[j] = (idx < n) ? hist[idx] : 0u;
        tsum += v[j];
    }
    s[t] = tsum; __syncthreads();
    for (int off = 1; off < 256; off <<= 1) {
        unsigned x = (t >= off) ? s[t - off] : 0u;
        __syncthreads();
        s[t] += x;
        __syncthreads();
    }
    if (t == 255) bsums[blockIdx.x] = s[255];
    unsigned run = s[t] - tsum;
    #pragma unroll
    for (int j = 0; j < 8; ++j) {
        int idx = start + j;
        if (idx < n) cursor[idx] = run;
        run += v[j];
    }
}

__global__ __launch_bounds__(256) void scan2_kernel(unsigned* __restrict__ bsums, int nb)
{
    __shared__ unsigned s[256];
    const int t = threadIdx.x;
    unsigned v = (t < nb) ? bsums[t] : 0u;
    s[t] = v; __syncthreads();
    for (int off = 1; off < 256; off <<= 1) {
        unsigned x = (t >= off) ? s[t - off] : 0u;
        __syncthreads();
        s[t] += x;
        __syncthreads();
    }
    if (t < nb) bsums[t] = s[t] - v;
}

__global__ __launch_bounds__(256) void scan3_kernel(
    unsigned* __restrict__ cursor, const unsigned* __restrict__ bsums, int n)
{
    int i  = blockIdx.x * blockDim.x + threadIdx.x;
    int st = gridDim.x * blockDim.x;
    for (int k = i; k < n; k += st) cursor[k] += bsums[k >> 11];
}

// pack (u,col,eid) into u64: u<<37 | col<<20 | eid   (u,col < 2^17, eid < 2^20)
__global__ __launch_bounds__(256) void scatter_kernel(
    const int* __restrict__ row, const int* __restrict__ col,
    unsigned* __restrict__ cursor, u64* __restrict__ srt, int E)
{
    int i  = blockIdx.x * blockDim.x + threadIdx.x;
    int st = gridDim.x * blockDim.x;
    for (int e = i; e < E; e += st) {
        int u = row[e];
        unsigned pos = atomicAdd(&cursor[u], 1u);
        srt[pos] = ((u64)(unsigned)u << 37) | ((u64)(unsigned)col[e] << 20) | (u64)(unsigned)e;
    }
}

// ---------------- edge kernel over sorted list: contiguous chunk per 16-lane group -------------
__global__ __launch_bounds__(256) void edge_sorted_kernel(
    const unsigned short* __restrict__ Pu, const unsigned short* __restrict__ Pi,
    const u64* __restrict__ srt, const float* __restrict__ W2,
    const float* __restrict__ b2, float* __restrict__ out, int E)
{
    const int lane16 = threadIdx.x & 15;
    const int c0     = lane16 * 8;
    const int g      = (blockIdx.x * blockDim.x + threadIdx.x) >> 4;
    const int ng     = (gridDim.x * blockDim.x) >> 4;
    const int per    = (E + ng - 1) / ng;
    int s = g * per;
    int t = s + per; if (t > E) t = E;

    float w2r[8];
    #pragma unroll
    for (int j = 0; j < 8; ++j) w2r[j] = W2[c0 + j];
    const float b2s = b2[0];

    #pragma unroll 2
    for (int e = s; e < t; ++e) {
        u64 pk = srt[e];
        int u   = (int)(pk >> 37);
        int ic  = (int)((pk >> 20) & 0x1FFFF);
        int eid = (int)(pk & 0xFFFFF);
        uint4 pu = *(const uint4*)(Pu + (size_t)u  * HH + c0);   // L1-hit for repeated u
        uint4 pi = *(const uint4*)(Pi + (size_t)ic * HH + c0);
        unsigned a[4] = {pu.x, pu.y, pu.z, pu.w};
        unsigned b[4] = {pi.x, pi.y, pi.z, pi.w};
        float p = 0.f;
        #pragma unroll
        for (int q = 0; q < 4; ++q) {
            float x0 = __builtin_bit_cast(float, a[q] << 16);
            float x1 = __builtin_bit_cast(float, a[q] & 0xFFFF0000u);
            float y0 = __builtin_bit_cast(float, b[q] << 16);
            float y1 = __builtin_bit_cast(float, b[q] & 0xFFFF0000u);
            p = fmaf(fmaxf(x0 + y0, 0.f), w2r[2 * q],     p);
            p = fmaf(fmaxf(x1 + y1, 0.f), w2r[2 * q + 1], p);
        }
        #pragma unroll
        for (int m = 8; m >= 1; m >>= 1)
            p += __shfl_xor(p, m, 64);
        if (lane16 == 0) out[eid] = p + b2s;
    }
}

// ---------------- fallback: unsorted bf16 gather ----------------
__global__ __launch_bounds__(256) void edge_bf16_kernel(
    const unsigned short* __restrict__ Pu, const unsigned short* __restrict__ Pi,
    const int* __restrict__ row, const int* __restrict__ col,
    const float* __restrict__ W2, const float* __restrict__ b2,
    float* __restrict__ out, int E)
{
    const int lane16 = threadIdx.x & 15;
    const int gid    = (blockIdx.x * blockDim.x + threadIdx.x) >> 4;
    const int stride = (gridDim.x * blockDim.x) >> 4;
    const int c0     = lane16 * 8;

    float w2r[8];
    #pragma unroll
    for (int j = 0; j < 8; ++j) w2r[j] = W2[c0 + j];
    const float b2s = b2[0];

    for (int e = gid; e < E; e += stride) {
        int u = row[e], it = col[e];
        uint4 pu = *(const uint4*)(Pu + (size_t)u  * HH + c0);
        uint4 pi = *(const uint4*)(Pi + (size_t)it * HH + c0);
        unsigned a[4] = {pu.x, pu.y, pu.z, pu.w};
        unsigned b[4] = {pi.x, pi.y, pi.z, pi.w};
        float p = 0.f;
        #pragma unroll
        for (int q = 0; q < 4; ++q) {
            float x0 = __builtin_bit_cast(float, a[q] << 16);
            float x1 = __builtin_bit_cast(float, a[q] & 0xFFFF0000u);
            float y0 = __builtin_bit_cast(float, b[q] << 16);
            float y1 = __builtin_bit_cast(float, b[q] & 0xFFFF0000u);
            p = fmaf(fmaxf(x0 + y0, 0.f), w2r[2 * q],     p);
            p = fmaf(fmaxf(x1 + y1, 0.f), w2r[2 * q + 1], p);
        }
        #pragma unroll
        for (int m = 8; m >= 1; m >>= 1)
            p += __shfl_xor(p, m, 64);
        if (lane16 == 0) out[e] = p + b2s;
    }
}

// ---------------- fallback (no workspace): direct per-edge fp32 compute ----------------
__global__ __launch_bounds__(256) void edge_direct_kernel(
    const float* __restrict__ zu, const float* __restrict__ zi,
    const int* __restrict__ row, const int* __restrict__ col,
    const float* __restrict__ W1, const float* __restrict__ b1,
    const float* __restrict__ W2, const float* __restrict__ b2,
    float* __restrict__ out, int E)
{
    const int lane   = threadIdx.x & 31;
    const int gid    = (blockIdx.x * blockDim.x + threadIdx.x) >> 5;
    const int stride = (gridDim.x * blockDim.x) >> 5;
    const int c0     = lane * 4;

    const float4 b1v = *(const float4*)(b1 + c0);
    const float4 w2v = *(const float4*)(W2 + c0);
    const float  b2s = b2[0];

    for (int e = gid; e < E; e += stride) {
        int u  = row[e];
        int it = col[e];
        const float* zur = zu + (size_t)u  * HH;
        const float* zir = zi + (size_t)it * HH;
        float4 acc = b1v;
        for (int k = 0; k < HH; ++k) {
            float  zk = zur[k];
            float4 w  = *(const float4*)(W1 + (size_t)k * HH + c0);
            acc.x = fmaf(zk, w.x, acc.x);
            acc.y = fmaf(zk, w.y, acc.y);
            acc.z = fmaf(zk, w.z, acc.z);
            acc.w = fmaf(zk, w.w, acc.w);
        }
        for (int k = 0; k < HH; ++k) {
            float  zk = zir[k];
            float4 w  = *(const float4*)(W1 + (size_t)(HH + k) * HH + c0);
            acc.x = fmaf(zk, w.x, acc.x);
            acc.y = fmaf(zk, w.y, acc.y);
            acc.z = fmaf(zk, w.z, acc.z);
            acc.w = fmaf(zk, w.w, acc.w);
        }
        float p = fmaxf(acc.x, 0.f) * w2v.x;
        p = fmaf(fmaxf(acc.y, 0.f), w2v.y, p);
        p = fmaf(fmaxf(acc.z, 0.f), w2v.z, p);
        p = fmaf(fmaxf(acc.w, 0.f), w2v.w, p);
        #pragma unroll
        for (int m = 16; m >= 1; m >>= 1)
            p += __shfl_xor(p, m, 64);
        if (lane == 0) out[e] = p + b2s;
    }
}

static inline size_t align256(size_t x) { return (x + 255) & ~(size_t)255; }

extern "C" void kernel_launch(void* const* d_in, const int* in_sizes, int n_in,
                              void* d_out, int out_size, void* d_ws, size_t ws_size,
                              hipStream_t stream)
{
    const float* z_user = (const float*)d_in[0];
    const float* z_item = (const float*)d_in[1];
    const int*   row    = (const int*)d_in[2];
    const int*   col    = (const int*)d_in[3];
    const float* W1     = (const float*)d_in[4];
    const float* b1     = (const float*)d_in[5];
    const float* W2     = (const float*)d_in[6];
    const float* b2     = (const float*)d_in[7];
    float*       out    = (float*)d_out;

    const int n_user = in_sizes[0] / HH;
    const int n_item = in_sizes[1] / HH;
    const int E      = in_sizes[2];

    // workspace layout
    const size_t offPu   = 0;
    const size_t offPi   = align256(offPu + (size_t)n_user * HH * 2);
    const size_t offSrt  = align256(offPi + (size_t)n_item * HH * 2);
    const size_t offCur  = align256(offSrt + (size_t)E * 8);
    const size_t offBs   = align256(offCur + (size_t)n_user * 4);
    const size_t offHist = align256(offBs + 1024 * 4);
    const size_t needSort = align256(offHist + (size_t)n_user * 4);
    const size_t needProj = align256(offPi + (size_t)n_item * HH * 2);

    const int nb1 = (n_user + 2047) >> 11;
    const bool sortable = (E <= (1 << 20)) && (n_user <= (1 << 17)) &&
                          (n_item <= (1 << 17)) && (nb1 <= 256) &&
                          (ws_size >= needSort);

    if (sortable) {
        unsigned short* Pu   = (unsigned short*)((char*)d_ws + offPu);
        unsigned short* Pi   = (unsigned short*)((char*)d_ws + offPi);
        u64*            srt  = (u64*)((char*)d_ws + offSrt);
        unsigned*       cur  = (unsigned*)((char*)d_ws + offCur);
        unsigned*       bs   = (unsigned*)((char*)d_ws + offBs);
        unsigned*       hist = (unsigned*)((char*)d_ws + offHist);

        hipMemsetAsync(hist, 0, (size_t)n_user * 4, stream);
        hist_kernel<<<1024, 256, 0, stream>>>(row, hist, E);
        scan1_kernel<<<nb1, 256, 0, stream>>>(hist, cur, bs, n_user);
        scan2_kernel<<<1, 256, 0, stream>>>(bs, nb1);
        scan3_kernel<<<256, 256, 0, stream>>>(cur, bs, n_user);
        scatter_kernel<<<1024, 256, 0, stream>>>(row, col, cur, srt, E);

        const int utiles  = (n_user + 63) >> 6;
        const int itiles  = (n_item + 63) >> 6;
        const int ublocks = (utiles + 1) >> 1;
        const int iblocks = (itiles + 1) >> 1;
        project_both_kernel<<<ublocks + iblocks, 256, 0, stream>>>(
            z_user, z_item, W1, b1, Pu, Pi, n_user, n_item, ublocks);
        edge_sorted_kernel<<<2048, 256, 0, stream>>>(Pu, Pi, srt, W2, b2, out, E);
    } else if (ws_size >= needProj) {
        unsigned short* Pu = (unsigned short*)((char*)d_ws + offPu);
        unsigned short* Pi = (unsigned short*)((char*)d_ws + offPi);
        const int utiles  = (n_user + 63) >> 6;
        const int itiles  = (n_item + 63) >> 6;
        const int ublocks = (utiles + 1) >> 1;
        const int iblocks = (itiles + 1) >> 1;
        project_both_kernel<<<ublocks + iblocks, 256, 0, stream>>>(
            z_user, z_item, W1, b1, Pu, Pi, n_user, n_item, ublocks);
        edge_bf16_kernel<<<2048, 256, 0, stream>>>(Pu, Pi, row, col, W2, b2, out, E);
    } else {
        edge_direct_kernel<<<2048, 256, 0, stream>>>(z_user, z_item, row, col, W1, b1, W2, b2, out, E);
    }
}

// Round 5
// 153.690 us; speedup vs baseline: 1.4817x; 1.4817x over previous
//
#include <hip/hip_runtime.h>

#define HH 128
#define NB_I 8      // item buckets (one per XCD)
#define NB_U 32     // user sub-buckets within an item bucket
#define NBKT (NB_I * NB_U)
#define SCHUNK 4096 // edges per scatter block
#define ECH 128     // edges per edge-kernel chunk
#define EBLK 1024   // edge kernel grid (128 blocks per item bucket)

typedef __attribute__((ext_vector_type(8))) short bf16x8;
typedef __attribute__((ext_vector_type(4))) float f32x4;
typedef unsigned long long u64;

__device__ inline unsigned short f2bf(float f) {
    unsigned u = __builtin_bit_cast(unsigned, f);
    u += 0x7FFF + ((u >> 16) & 1);   // round to nearest even
    return (unsigned short)(u >> 16);
}

__device__ inline int bucket_of(int u, int i, unsigned n_user, unsigned n_item) {
    unsigned bi = ((unsigned)i * NB_I) / n_item;   // < 8
    unsigned bu = ((unsigned)u * NB_U) / n_user;   // < 32
    return (int)(bi * NB_U + bu);
}

// ---------------- fused MFMA projection: both tables in one launch ----------------
__global__ __launch_bounds__(256) void project_both_kernel(
    const float* __restrict__ Zu, const float* __restrict__ Zi,
    const float* __restrict__ W1, const float* __restrict__ b1,
    unsigned short* __restrict__ Pu, unsigned short* __restrict__ Pi,
    int n_user, int n_item, int ublocks)
{
    __shared__ unsigned short sWt[128 * 128];    // 32 KB, chunk-XOR swizzled
    __shared__ unsigned short sOut[64 * 136];    // 17 KB

    const bool isUser = ((int)blockIdx.x < ublocks);
    const float* __restrict__ Z = isUser ? Zu : Zi;
    const float* __restrict__ W = isUser ? W1 : (W1 + HH * HH);
    unsigned short* __restrict__ P = isUser ? Pu : Pi;
    const int nrows  = isUser ? n_user : n_item;
    const int ntiles = (nrows + 63) >> 6;
    const int tbase  = (isUser ? (int)blockIdx.x : ((int)blockIdx.x - ublocks)) * 2;

    const int t    = threadIdx.x;
    const int wave = t >> 6;
    const int lane = t & 63;
    const int l16  = lane & 15;
    const int lk8  = (lane >> 4) * 8;

    #pragma unroll 4
    for (int i = 0; i < 16; ++i) {
        int idx = t + i * 256;
        int k   = idx >> 5;
        int c4  = (idx & 31) * 4;
        float4 w = *(const float4*)(W + (size_t)k * HH + c4);
        float wv[4] = {w.x, w.y, w.z, w.w};
        #pragma unroll
        for (int j = 0; j < 4; ++j) {
            int c = c4 + j;
            sWt[c * 128 + (((k >> 3) ^ (c & 15)) << 3) + (k & 7)] = f2bf(wv[j]);
        }
    }

    float b1r[8];
    #pragma unroll
    for (int nt = 0; nt < 8; ++nt)
        b1r[nt] = isUser ? b1[nt * 16 + l16] : 0.f;

    __syncthreads();

    #pragma unroll 1
    for (int s = 0; s < 2; ++s) {
        const int tile = tbase + s;
        if (tile >= ntiles) break;
        const int rbase = tile << 6;

        f32x4 acc[8];
        #pragma unroll
        for (int nt = 0; nt < 8; ++nt) acc[nt] = (f32x4)0.f;

        int m = rbase + wave * 16 + l16;
        if (m > nrows - 1) m = nrows - 1;
        const float* Zrow = Z + (size_t)m * HH;

        #pragma unroll
        for (int kk = 0; kk < 4; ++kk) {
            float4 z0 = *(const float4*)(Zrow + kk * 32 + lk8);
            float4 z1 = *(const float4*)(Zrow + kk * 32 + lk8 + 4);
            bf16x8 a;
            a[0] = (short)f2bf(z0.x); a[1] = (short)f2bf(z0.y);
            a[2] = (short)f2bf(z0.z); a[3] = (short)f2bf(z0.w);
            a[4] = (short)f2bf(z1.x); a[5] = (short)f2bf(z1.y);
            a[6] = (short)f2bf(z1.z); a[7] = (short)f2bf(z1.w);

            const int chunkSw = ((kk * 4 + (lane >> 4)) ^ l16) << 3;
            #pragma unroll
            for (int nt = 0; nt < 8; ++nt) {
                int c = nt * 16 + l16;
                bf16x8 b = *(const bf16x8*)(sWt + c * 128 + chunkSw);
                acc[nt] = __builtin_amdgcn_mfma_f32_16x16x32_bf16(a, b, acc[nt], 0, 0, 0);
            }
        }

        __syncthreads();
        #pragma unroll
        for (int nt = 0; nt < 8; ++nt) {
            int colc = nt * 16 + l16;
            #pragma unroll
            for (int r = 0; r < 4; ++r) {
                int orow = wave * 16 + (lane >> 4) * 4 + r;
                sOut[orow * 136 + colc] = f2bf(acc[nt][r] + b1r[nt]);
            }
        }
        __syncthreads();
        #pragma unroll
        for (int i = 0; i < 4; ++i) {
            int idx = t + i * 256;
            int r   = idx >> 4;
            int ch  = idx & 15;
            int grow = rbase + r;
            if (grow < nrows)
                *(uint4*)(P + (size_t)grow * HH + ch * 8) =
                    *(const uint4*)(sOut + r * 136 + ch * 8);
        }
    }
}

// ---------------- 256-bucket histogram ----------------
__global__ __launch_bounds__(256) void hist256_kernel(
    const int* __restrict__ row, const int* __restrict__ col,
    unsigned* __restrict__ hist, int E, unsigned n_user, unsigned n_item)
{
    __shared__ unsigned lh[NBKT];
    const int t = threadIdx.x;
    lh[t] = 0;
    __syncthreads();
    int i  = blockIdx.x * blockDim.x + t;
    int st = gridDim.x * blockDim.x;
    for (int e = i; e < E; e += st)
        atomicAdd(&lh[bucket_of(row[e], col[e], n_user, n_item)], 1u);
    __syncthreads();
    if (lh[t]) atomicAdd(&hist[t], lh[t]);
}

// ---------------- exclusive scan of 256 bucket counts (1 block) ----------------
__global__ __launch_bounds__(256) void scan256_kernel(
    const unsigned* __restrict__ hist, unsigned* __restrict__ cursor,
    unsigned* __restrict__ bstart)
{
    __shared__ unsigned s[NBKT];
    const int t = threadIdx.x;
    unsigned v = hist[t];
    s[t] = v; __syncthreads();
    for (int off = 1; off < NBKT; off <<= 1) {
        unsigned x = (t >= off) ? s[t - off] : 0u;
        __syncthreads();
        s[t] += x;
        __syncthreads();
    }
    unsigned excl = s[t] - v;
    cursor[t] = excl;
    bstart[t] = excl;
    if (t == NBKT - 1) bstart[NBKT] = s[t];
}

// ---------------- two-pass block-local binning scatter ----------------
// pack (u,i,eid): u<<37 | i<<20 | eid
__global__ __launch_bounds__(256) void scatter256_kernel(
    const int* __restrict__ row, const int* __restrict__ col,
    unsigned* __restrict__ cursor, u64* __restrict__ srt,
    int E, unsigned n_user, unsigned n_item)
{
    __shared__ unsigned lh[NBKT];
    __shared__ unsigned gb[NBKT];
    __shared__ unsigned lc[NBKT];
    const int t    = threadIdx.x;
    const int base = blockIdx.x * SCHUNK;
    lh[t] = 0;
    __syncthreads();
    #pragma unroll
    for (int k = 0; k < SCHUNK / 256; ++k) {
        int e = base + k * 256 + t;
        if (e < E) atomicAdd(&lh[bucket_of(row[e], col[e], n_user, n_item)], 1u);
    }
    __syncthreads();
    gb[t] = lh[t] ? atomicAdd(&cursor[t], lh[t]) : 0u;
    lc[t] = 0;
    __syncthreads();
    #pragma unroll
    for (int k = 0; k < SCHUNK / 256; ++k) {
        int e = base + k * 256 + t;
        if (e < E) {
            int u = row[e], ic = col[e];
            int b = bucket_of(u, ic, n_user, n_item);
            unsigned r = atomicAdd(&lc[b], 1u);
            srt[gb[b] + r] =
                ((u64)(unsigned)u << 37) | ((u64)(unsigned)ic << 20) | (u64)(unsigned)e;
        }
    }
}

// ---------------- edge kernel over bucketed list, XCD-pinned item buckets ----------------
__global__ __launch_bounds__(256) void edge_sorted_kernel(
    const unsigned short* __restrict__ Pu, const unsigned short* __restrict__ Pi,
    const u64* __restrict__ srt, const unsigned* __restrict__ bstart,
    const float* __restrict__ W2, const float* __restrict__ b2,
    float* __restrict__ out)
{
    const int j   = blockIdx.x;
    const int bi  = j & (NB_I - 1);          // item bucket -> XCD (round-robin dispatch)
    const int jj  = j >> 3;                  // 0..127
    const int NBLK = EBLK / NB_I;            // 128 blocks per item bucket
    const int S = (int)bstart[bi * NB_U];
    const int T = (int)bstart[(bi + 1) * NB_U];

    const int g      = threadIdx.x >> 4;     // 16 groups per block
    const int lane16 = threadIdx.x & 15;
    const int c0     = lane16 * 8;

    float w2r[8];
    #pragma unroll
    for (int q = 0; q < 8; ++q) w2r[q] = W2[c0 + q];
    const float b2s = b2[0];

    const int nch = (T - S + ECH - 1) / ECH;
    for (int c = jj; c < nch; c += NBLK) {   // bu-ordered chunks: temporal locality in Pu
        int cb = S + c * ECH;
        int ce = cb + ECH; if (ce > T) ce = T;
        for (int e = cb + g; e < ce; e += 16) {
            u64 pk = srt[e];
            int u   = (int)(pk >> 37);
            int ic  = (int)((pk >> 20) & 0x1FFFF);
            int eid = (int)(pk & 0xFFFFF);
            uint4 pu = *(const uint4*)(Pu + (size_t)u  * HH + c0);
            uint4 pi = *(const uint4*)(Pi + (size_t)ic * HH + c0);
            unsigned a[4] = {pu.x, pu.y, pu.z, pu.w};
            unsigned b[4] = {pi.x, pi.y, pi.z, pi.w};
            float p = 0.f;
            #pragma unroll
            for (int q = 0; q < 4; ++q) {
                float x0 = __builtin_bit_cast(float, a[q] << 16);
                float x1 = __builtin_bit_cast(float, a[q] & 0xFFFF0000u);
                float y0 = __builtin_bit_cast(float, b[q] << 16);
                float y1 = __builtin_bit_cast(float, b[q] & 0xFFFF0000u);
                p = fmaf(fmaxf(x0 + y0, 0.f), w2r[2 * q],     p);
                p = fmaf(fmaxf(x1 + y1, 0.f), w2r[2 * q + 1], p);
            }
            #pragma unroll
            for (int m = 8; m >= 1; m >>= 1)
                p += __shfl_xor(p, m, 64);
            if (lane16 == 0) out[eid] = p + b2s;
        }
    }
}

// ---------------- fallback: unsorted bf16 gather ----------------
__global__ __launch_bounds__(256) void edge_bf16_kernel(
    const unsigned short* __restrict__ Pu, const unsigned short* __restrict__ Pi,
    const int* __restrict__ row, const int* __restrict__ col,
    const float* __restrict__ W2, const float* __restrict__ b2,
    float* __restrict__ out, int E)
{
    const int lane16 = threadIdx.x & 15;
    const int gid    = (blockIdx.x * blockDim.x + threadIdx.x) >> 4;
    const int stride = (gridDim.x * blockDim.x) >> 4;
    const int c0     = lane16 * 8;

    float w2r[8];
    #pragma unroll
    for (int q = 0; q < 8; ++q) w2r[q] = W2[c0 + q];
    const float b2s = b2[0];

    for (int e = gid; e < E; e += stride) {
        int u = row[e], it = col[e];
        uint4 pu = *(const uint4*)(Pu + (size_t)u  * HH + c0);
        uint4 pi = *(const uint4*)(Pi + (size_t)it * HH + c0);
        unsigned a[4] = {pu.x, pu.y, pu.z, pu.w};
        unsigned b[4] = {pi.x, pi.y, pi.z, pi.w};
        float p = 0.f;
        #pragma unroll
        for (int q = 0; q < 4; ++q) {
            float x0 = __builtin_bit_cast(float, a[q] << 16);
            float x1 = __builtin_bit_cast(float, a[q] & 0xFFFF0000u);
            float y0 = __builtin_bit_cast(float, b[q] << 16);
            float y1 = __builtin_bit_cast(float, b[q] & 0xFFFF0000u);
            p = fmaf(fmaxf(x0 + y0, 0.f), w2r[2 * q],     p);
            p = fmaf(fmaxf(x1 + y1, 0.f), w2r[2 * q + 1], p);
        }
        #pragma unroll
        for (int m = 8; m >= 1; m >>= 1)
            p += __shfl_xor(p, m, 64);
        if (lane16 == 0) out[e] = p + b2s;
    }
}

// ---------------- fallback (no workspace): direct per-edge fp32 compute ----------------
__global__ __launch_bounds__(256) void edge_direct_kernel(
    const float* __restrict__ zu, const float* __restrict__ zi,
    const int* __restrict__ row, const int* __restrict__ col,
    const float* __restrict__ W1, const float* __restrict__ b1,
    const float* __restrict__ W2, const float* __restrict__ b2,
    float* __restrict__ out, int E)
{
    const int lane   = threadIdx.x & 31;
    const int gid    = (blockIdx.x * blockDim.x + threadIdx.x) >> 5;
    const int stride = (gridDim.x * blockDim.x) >> 5;
    const int c0     = lane * 4;

    const float4 b1v = *(const float4*)(b1 + c0);
    const float4 w2v = *(const float4*)(W2 + c0);
    const float  b2s = b2[0];

    for (int e = gid; e < E; e += stride) {
        int u  = row[e];
        int it = col[e];
        const float* zur = zu + (size_t)u  * HH;
        const float* zir = zi + (size_t)it * HH;
        float4 acc = b1v;
        for (int k = 0; k < HH; ++k) {
            float  zk = zur[k];
            float4 w  = *(const float4*)(W1 + (size_t)k * HH + c0);
            acc.x = fmaf(zk, w.x, acc.x);
            acc.y = fmaf(zk, w.y, acc.y);
            acc.z = fmaf(zk, w.z, acc.z);
            acc.w = fmaf(zk, w.w, acc.w);
        }
        for (int k = 0; k < HH; ++k) {
            float  zk = zir[k];
            float4 w  = *(const float4*)(W1 + (size_t)(HH + k) * HH + c0);
            acc.x = fmaf(zk, w.x, acc.x);
            acc.y = fmaf(zk, w.y, acc.y);
            acc.z = fmaf(zk, w.z, acc.z);
            acc.w = fmaf(zk, w.w, acc.w);
        }
        float p = fmaxf(acc.x, 0.f) * w2v.x;
        p = fmaf(fmaxf(acc.y, 0.f), w2v.y, p);
        p = fmaf(fmaxf(acc.z, 0.f), w2v.z, p);
        p = fmaf(fmaxf(acc.w, 0.f), w2v.w, p);
        #pragma unroll
        for (int m = 16; m >= 1; m >>= 1)
            p += __shfl_xor(p, m, 64);
        if (lane == 0) out[e] = p + b2s;
    }
}

static inline size_t align256(size_t x) { return (x + 255) & ~(size_t)255; }

extern "C" void kernel_launch(void* const* d_in, const int* in_sizes, int n_in,
                              void* d_out, int out_size, void* d_ws, size_t ws_size,
                              hipStream_t stream)
{
    const float* z_user = (const float*)d_in[0];
    const float* z_item = (const float*)d_in[1];
    const int*   row    = (const int*)d_in[2];
    const int*   col    = (const int*)d_in[3];
    const float* W1     = (const float*)d_in[4];
    const float* b1     = (const float*)d_in[5];
    const float* W2     = (const float*)d_in[6];
    const float* b2     = (const float*)d_in[7];
    float*       out    = (float*)d_out;

    const int n_user = in_sizes[0] / HH;
    const int n_item = in_sizes[1] / HH;
    const int E      = in_sizes[2];

    // workspace layout
    const size_t offPu   = 0;
    const size_t offPi   = align256(offPu + (size_t)n_user * HH * 2);
    const size_t offSrt  = align256(offPi + (size_t)n_item * HH * 2);
    const size_t offCur  = align256(offSrt + (size_t)E * 8);
    const size_t offHist = align256(offCur + NBKT * 4);
    const size_t offBst  = align256(offHist + NBKT * 4);
    const size_t needSort = align256(offBst + (NBKT + 1) * 4);
    const size_t needProj = align256(offPi + (size_t)n_item * HH * 2);

    const bool sortable = (E <= (1 << 20)) && (n_user <= (1 << 17)) &&
                          (n_item <= (1 << 17)) && (ws_size >= needSort);

    const int utiles  = (n_user + 63) >> 6;
    const int itiles  = (n_item + 63) >> 6;
    const int ublocks = (utiles + 1) >> 1;
    const int iblocks = (itiles + 1) >> 1;

    if (sortable) {
        unsigned short* Pu   = (unsigned short*)((char*)d_ws + offPu);
        unsigned short* Pi   = (unsigned short*)((char*)d_ws + offPi);
        u64*            srt  = (u64*)((char*)d_ws + offSrt);
        unsigned*       cur  = (unsigned*)((char*)d_ws + offCur);
        unsigned*       hist = (unsigned*)((char*)d_ws + offHist);
        unsigned*       bst  = (unsigned*)((char*)d_ws + offBst);

        hipMemsetAsync(hist, 0, NBKT * 4, stream);
        hist256_kernel<<<512, 256, 0, stream>>>(row, col, hist, E,
                                                (unsigned)n_user, (unsigned)n_item);
        scan256_kernel<<<1, 256, 0, stream>>>(hist, cur, bst);
        scatter256_kernel<<<(E + SCHUNK - 1) / SCHUNK, 256, 0, stream>>>(
            row, col, cur, srt, E, (unsigned)n_user, (unsigned)n_item);
        project_both_kernel<<<ublocks + iblocks, 256, 0, stream>>>(
            z_user, z_item, W1, b1, Pu, Pi, n_user, n_item, ublocks);
        edge_sorted_kernel<<<EBLK, 256, 0, stream>>>(Pu, Pi, srt, bst, W2, b2, out);
    } else if (ws_size >= needProj) {
        unsigned short* Pu = (unsigned short*)((char*)d_ws + offPu);
        unsigned short* Pi = (unsigned short*)((char*)d_ws + offPi);
        project_both_kernel<<<ublocks + iblocks, 256, 0, stream>>>(
            z_user, z_item, W1, b1, Pu, Pi, n_user, n_item, ublocks);
        edge_bf16_kernel<<<2048, 256, 0, stream>>>(Pu, Pi, row, col, W2, b2, out, E);
    } else {
        edge_direct_kernel<<<2048, 256, 0, stream>>>(z_user, z_item, row, col, W1, b1, W2, b2, out, E);
    }
}

// Round 6
// 113.456 us; speedup vs baseline: 2.0072x; 1.3546x over previous
//
#include <hip/hip_runtime.h>

#define HH 128
#define BU 8        // user buckets (one per XCD) -> Pu slice 3.2MB pinned in L2
#define BI 32       // item sub-buckets            -> Pi slice 0.4MB streamed
#define NBKT (BU * BI)
#define SCHUNK 4096 // edges per scatter block

typedef __attribute__((ext_vector_type(8))) short bf16x8;
typedef __attribute__((ext_vector_type(4))) float f32x4;
typedef unsigned long long u64;

__device__ inline unsigned short f2bf(float f) {
    unsigned u = __builtin_bit_cast(unsigned, f);
    u += 0x7FFF + ((u >> 16) & 1);   // round to nearest even
    return (unsigned short)(u >> 16);
}

__device__ inline int bucket_of(int u, int i, unsigned n_user, unsigned n_item) {
    unsigned uc = ((unsigned)u * BU) / n_user;   // < 8
    unsigned ic = ((unsigned)i * BI) / n_item;   // < 32
    return (int)(uc * BI + ic);
}

// ---------------- fused MFMA projection: both tables in one launch ----------------
__global__ __launch_bounds__(256) void project_both_kernel(
    const float* __restrict__ Zu, const float* __restrict__ Zi,
    const float* __restrict__ W1, const float* __restrict__ b1,
    unsigned short* __restrict__ Pu, unsigned short* __restrict__ Pi,
    int n_user, int n_item, int ublocks)
{
    __shared__ unsigned short sWt[128 * 128];    // 32 KB, chunk-XOR swizzled
    __shared__ unsigned short sOut[64 * 136];    // 17 KB

    const bool isUser = ((int)blockIdx.x < ublocks);
    const float* __restrict__ Z = isUser ? Zu : Zi;
    const float* __restrict__ W = isUser ? W1 : (W1 + HH * HH);
    unsigned short* __restrict__ P = isUser ? Pu : Pi;
    const int nrows  = isUser ? n_user : n_item;
    const int ntiles = (nrows + 63) >> 6;
    const int tbase  = (isUser ? (int)blockIdx.x : ((int)blockIdx.x - ublocks)) * 2;

    const int t    = threadIdx.x;
    const int wave = t >> 6;
    const int lane = t & 63;
    const int l16  = lane & 15;
    const int lk8  = (lane >> 4) * 8;

    #pragma unroll 4
    for (int i = 0; i < 16; ++i) {
        int idx = t + i * 256;
        int k   = idx >> 5;
        int c4  = (idx & 31) * 4;
        float4 w = *(const float4*)(W + (size_t)k * HH + c4);
        float wv[4] = {w.x, w.y, w.z, w.w};
        #pragma unroll
        for (int j = 0; j < 4; ++j) {
            int c = c4 + j;
            sWt[c * 128 + (((k >> 3) ^ (c & 15)) << 3) + (k & 7)] = f2bf(wv[j]);
        }
    }

    float b1r[8];
    #pragma unroll
    for (int nt = 0; nt < 8; ++nt)
        b1r[nt] = isUser ? b1[nt * 16 + l16] : 0.f;

    __syncthreads();

    #pragma unroll 1
    for (int s = 0; s < 2; ++s) {
        const int tile = tbase + s;
        if (tile >= ntiles) break;
        const int rbase = tile << 6;

        f32x4 acc[8];
        #pragma unroll
        for (int nt = 0; nt < 8; ++nt) acc[nt] = (f32x4)0.f;

        int m = rbase + wave * 16 + l16;
        if (m > nrows - 1) m = nrows - 1;
        const float* Zrow = Z + (size_t)m * HH;

        #pragma unroll
        for (int kk = 0; kk < 4; ++kk) {
            float4 z0 = *(const float4*)(Zrow + kk * 32 + lk8);
            float4 z1 = *(const float4*)(Zrow + kk * 32 + lk8 + 4);
            bf16x8 a;
            a[0] = (short)f2bf(z0.x); a[1] = (short)f2bf(z0.y);
            a[2] = (short)f2bf(z0.z); a[3] = (short)f2bf(z0.w);
            a[4] = (short)f2bf(z1.x); a[5] = (short)f2bf(z1.y);
            a[6] = (short)f2bf(z1.z); a[7] = (short)f2bf(z1.w);

            const int chunkSw = ((kk * 4 + (lane >> 4)) ^ l16) << 3;
            #pragma unroll
            for (int nt = 0; nt < 8; ++nt) {
                int c = nt * 16 + l16;
                bf16x8 b = *(const bf16x8*)(sWt + c * 128 + chunkSw);
                acc[nt] = __builtin_amdgcn_mfma_f32_16x16x32_bf16(a, b, acc[nt], 0, 0, 0);
            }
        }

        __syncthreads();
        #pragma unroll
        for (int nt = 0; nt < 8; ++nt) {
            int colc = nt * 16 + l16;
            #pragma unroll
            for (int r = 0; r < 4; ++r) {
                int orow = wave * 16 + (lane >> 4) * 4 + r;
                sOut[orow * 136 + colc] = f2bf(acc[nt][r] + b1r[nt]);
            }
        }
        __syncthreads();
        #pragma unroll
        for (int i = 0; i < 4; ++i) {
            int idx = t + i * 256;
            int r   = idx >> 4;
            int ch  = idx & 15;
            int grow = rbase + r;
            if (grow < nrows)
                *(uint4*)(P + (size_t)grow * HH + ch * 8) =
                    *(const uint4*)(sOut + r * 136 + ch * 8);
        }
    }
}

// ---------------- bucket region init (fixed capacity, no hist/scan) ----------------
__global__ __launch_bounds__(256) void init_cursor_kernel(unsigned* __restrict__ cursor, int cap)
{
    cursor[threadIdx.x] = (unsigned)(threadIdx.x * cap);
}

// ---------------- two-pass block-local binning scatter; also emits invpos ----------------
__global__ __launch_bounds__(256) void scatter_kernel(
    const int* __restrict__ row, const int* __restrict__ col,
    unsigned* __restrict__ cursor, u64* __restrict__ srt,
    unsigned* __restrict__ invpos, int E, unsigned n_user, unsigned n_item)
{
    __shared__ unsigned lh[NBKT];
    __shared__ unsigned gb[NBKT];
    __shared__ unsigned lc[NBKT];
    const int t    = threadIdx.x;
    const int base = blockIdx.x * SCHUNK;

    int uu[SCHUNK / 256], ii[SCHUNK / 256], bk[SCHUNK / 256];

    lh[t] = 0;
    __syncthreads();
    #pragma unroll
    for (int k = 0; k < SCHUNK / 256; ++k) {
        int e = base + k * 256 + t;
        bk[k] = -1;
        if (e < E) {
            uu[k] = row[e]; ii[k] = col[e];
            bk[k] = bucket_of(uu[k], ii[k], n_user, n_item);
            atomicAdd(&lh[bk[k]], 1u);
        }
    }
    __syncthreads();
    gb[t] = lh[t] ? atomicAdd(&cursor[t], lh[t]) : 0u;
    lc[t] = 0;
    __syncthreads();
    #pragma unroll
    for (int k = 0; k < SCHUNK / 256; ++k) {
        int e = base + k * 256 + t;
        if (e < E) {
            int b = bk[k];
            unsigned r   = atomicAdd(&lc[b], 1u);
            unsigned pos = gb[b] + r;
            srt[pos]  = ((u64)(unsigned)uu[k] << 32) | (u64)(unsigned)ii[k];
            invpos[e] = pos;                         // coalesced in e-order
        }
    }
}

// ---------------- edge kernel over bucketed list ----------------
// grid 2048 x 256: uc = blk&7 -> XCD (Pu slice pinned in that XCD's L2);
// 4096 groups per uc sweep the 32 item sub-buckets in order; coalesced psorted writes.
__global__ __launch_bounds__(256) void edge_sorted_kernel(
    const unsigned short* __restrict__ Pu, const unsigned short* __restrict__ Pi,
    const u64* __restrict__ srt, const unsigned* __restrict__ cursor,
    const float* __restrict__ W2, const float* __restrict__ b2,
    float* __restrict__ psorted, int cap)
{
    const int uc     = blockIdx.x & (BU - 1);
    const int jj     = blockIdx.x >> 3;          // 0..255
    const int g      = threadIdx.x >> 4;         // 0..15
    const int lane16 = threadIdx.x & 15;
    const int gg     = jj * 16 + g;              // 0..4095
    const int c0     = lane16 * 8;

    float w2r[8];
    #pragma unroll
    for (int q = 0; q < 8; ++q) w2r[q] = W2[c0 + q];
    const float b2s = b2[0];

    #pragma unroll 1
    for (int ic = 0; ic < BI; ++ic) {
        const int b    = uc * BI + ic;
        const int S    = b * cap;
        const int Tend = (int)cursor[b];
        for (int p = S + gg; p < Tend; p += BU * 512) {   // 4096 groups per uc
            u64 pk = srt[p];
            int u  = (int)(pk >> 32);
            int it = (int)(pk & 0xFFFFFFFFu);
            uint4 pu = *(const uint4*)(Pu + (size_t)u  * HH + c0);
            uint4 pi = *(const uint4*)(Pi + (size_t)it * HH + c0);
            unsigned a[4] = {pu.x, pu.y, pu.z, pu.w};
            unsigned c[4] = {pi.x, pi.y, pi.z, pi.w};
            float pv = 0.f;
            #pragma unroll
            for (int q = 0; q < 4; ++q) {
                float x0 = __builtin_bit_cast(float, a[q] << 16);
                float x1 = __builtin_bit_cast(float, a[q] & 0xFFFF0000u);
                float y0 = __builtin_bit_cast(float, c[q] << 16);
                float y1 = __builtin_bit_cast(float, c[q] & 0xFFFF0000u);
                pv = fmaf(fmaxf(x0 + y0, 0.f), w2r[2 * q],     pv);
                pv = fmaf(fmaxf(x1 + y1, 0.f), w2r[2 * q + 1], pv);
            }
            #pragma unroll
            for (int m = 8; m >= 1; m >>= 1)
                pv += __shfl_xor(pv, m, 64);
            if (lane16 == 0) psorted[p] = pv + b2s;  // 16 groups/block -> 64B-contig
        }
    }
}

// ---------------- permutation: out[e] = psorted[invpos[e]] ----------------
__global__ __launch_bounds__(256) void permute_kernel(
    const float* __restrict__ psorted, const unsigned* __restrict__ invpos,
    float* __restrict__ out, int E)
{
    int i  = blockIdx.x * blockDim.x + threadIdx.x;
    int st = gridDim.x * blockDim.x;
    for (int e = i; e < E; e += st)
        out[e] = psorted[invpos[e]];
}

// ---------------- fallback: unsorted bf16 gather ----------------
__global__ __launch_bounds__(256) void edge_bf16_kernel(
    const unsigned short* __restrict__ Pu, const unsigned short* __restrict__ Pi,
    const int* __restrict__ row, const int* __restrict__ col,
    const float* __restrict__ W2, const float* __restrict__ b2,
    float* __restrict__ out, int E)
{
    const int lane16 = threadIdx.x & 15;
    const int gid    = (blockIdx.x * blockDim.x + threadIdx.x) >> 4;
    const int stride = (gridDim.x * blockDim.x) >> 4;
    const int c0     = lane16 * 8;

    float w2r[8];
    #pragma unroll
    for (int q = 0; q < 8; ++q) w2r[q] = W2[c0 + q];
    const float b2s = b2[0];

    for (int e = gid; e < E; e += stride) {
        int u = row[e], it = col[e];
        uint4 pu = *(const uint4*)(Pu + (size_t)u  * HH + c0);
        uint4 pi = *(const uint4*)(Pi + (size_t)it * HH + c0);
        unsigned a[4] = {pu.x, pu.y, pu.z, pu.w};
        unsigned b[4] = {pi.x, pi.y, pi.z, pi.w};
        float p = 0.f;
        #pragma unroll
        for (int q = 0; q < 4; ++q) {
            float x0 = __builtin_bit_cast(float, a[q] << 16);
            float x1 = __builtin_bit_cast(float, a[q] & 0xFFFF0000u);
            float y0 = __builtin_bit_cast(float, b[q] << 16);
            float y1 = __builtin_bit_cast(float, b[q] & 0xFFFF0000u);
            p = fmaf(fmaxf(x0 + y0, 0.f), w2r[2 * q],     p);
            p = fmaf(fmaxf(x1 + y1, 0.f), w2r[2 * q + 1], p);
        }
        #pragma unroll
        for (int m = 8; m >= 1; m >>= 1)
            p += __shfl_xor(p, m, 64);
        if (lane16 == 0) out[e] = p + b2s;
    }
}

// ---------------- fallback (no workspace): direct per-edge fp32 compute ----------------
__global__ __launch_bounds__(256) void edge_direct_kernel(
    const float* __restrict__ zu, const float* __restrict__ zi,
    const int* __restrict__ row, const int* __restrict__ col,
    const float* __restrict__ W1, const float* __restrict__ b1,
    const float* __restrict__ W2, const float* __restrict__ b2,
    float* __restrict__ out, int E)
{
    const int lane   = threadIdx.x & 31;
    const int gid    = (blockIdx.x * blockDim.x + threadIdx.x) >> 5;
    const int stride = (gridDim.x * blockDim.x) >> 5;
    const int c0     = lane * 4;

    const float4 b1v = *(const float4*)(b1 + c0);
    const float4 w2v = *(const float4*)(W2 + c0);
    const float  b2s = b2[0];

    for (int e = gid; e < E; e += stride) {
        int u  = row[e];
        int it = col[e];
        const float* zur = zu + (size_t)u  * HH;
        const float* zir = zi + (size_t)it * HH;
        float4 acc = b1v;
        for (int k = 0; k < HH; ++k) {
            float  zk = zur[k];
            float4 w  = *(const float4*)(W1 + (size_t)k * HH + c0);
            acc.x = fmaf(zk, w.x, acc.x);
            acc.y = fmaf(zk, w.y, acc.y);
            acc.z = fmaf(zk, w.z, acc.z);
            acc.w = fmaf(zk, w.w, acc.w);
        }
        for (int k = 0; k < HH; ++k) {
            float  zk = zir[k];
            float4 w  = *(const float4*)(W1 + (size_t)(HH + k) * HH + c0);
            acc.x = fmaf(zk, w.x, acc.x);
            acc.y = fmaf(zk, w.y, acc.y);
            acc.z = fmaf(zk, w.z, acc.z);
            acc.w = fmaf(zk, w.w, acc.w);
        }
        float p = fmaxf(acc.x, 0.f) * w2v.x;
        p = fmaf(fmaxf(acc.y, 0.f), w2v.y, p);
        p = fmaf(fmaxf(acc.z, 0.f), w2v.z, p);
        p = fmaf(fmaxf(acc.w, 0.f), w2v.w, p);
        #pragma unroll
        for (int m = 16; m >= 1; m >>= 1)
            p += __shfl_xor(p, m, 64);
        if (lane == 0) out[e] = p + b2s;
    }
}

static inline size_t align256(size_t x) { return (x + 255) & ~(size_t)255; }

extern "C" void kernel_launch(void* const* d_in, const int* in_sizes, int n_in,
                              void* d_out, int out_size, void* d_ws, size_t ws_size,
                              hipStream_t stream)
{
    const float* z_user = (const float*)d_in[0];
    const float* z_item = (const float*)d_in[1];
    const int*   row    = (const int*)d_in[2];
    const int*   col    = (const int*)d_in[3];
    const float* W1     = (const float*)d_in[4];
    const float* b1     = (const float*)d_in[5];
    const float* W2     = (const float*)d_in[6];
    const float* b2     = (const float*)d_in[7];
    float*       out    = (float*)d_out;

    const int n_user = in_sizes[0] / HH;
    const int n_item = in_sizes[1] / HH;
    const int E      = in_sizes[2];

    // fixed-capacity bucket regions: cap = 1.25 * mean + 64 (uniform dist => +15 sigma)
    const int capBase = (E + NBKT - 1) / NBKT;
    const int cap     = capBase + capBase / 4 + 64;
    const size_t padded = (size_t)cap * NBKT;

    // workspace layout
    const size_t offPu  = 0;
    const size_t offPi  = align256(offPu  + (size_t)n_user * HH * 2);
    const size_t offSrt = align256(offPi  + (size_t)n_item * HH * 2);
    const size_t offPs  = align256(offSrt + padded * 8);
    const size_t offInv = align256(offPs  + padded * 4);
    const size_t offCur = align256(offInv + (size_t)E * 4);
    const size_t needSort = align256(offCur + NBKT * 4);
    const size_t needProj = align256(offPi + (size_t)n_item * HH * 2);

    const bool sortable = (n_user >= BU) && (n_item >= BI) &&
                          (n_user <= (1 << 17)) && (ws_size >= needSort);

    const int utiles  = (n_user + 63) >> 6;
    const int itiles  = (n_item + 63) >> 6;
    const int ublocks = (utiles + 1) >> 1;
    const int iblocks = (itiles + 1) >> 1;

    if (sortable) {
        unsigned short* Pu  = (unsigned short*)((char*)d_ws + offPu);
        unsigned short* Pi  = (unsigned short*)((char*)d_ws + offPi);
        u64*            srt = (u64*)((char*)d_ws + offSrt);
        float*          ps  = (float*)((char*)d_ws + offPs);
        unsigned*       inv = (unsigned*)((char*)d_ws + offInv);
        unsigned*       cur = (unsigned*)((char*)d_ws + offCur);

        init_cursor_kernel<<<1, NBKT, 0, stream>>>(cur, cap);
        scatter_kernel<<<(E + SCHUNK - 1) / SCHUNK, 256, 0, stream>>>(
            row, col, cur, srt, inv, E, (unsigned)n_user, (unsigned)n_item);
        project_both_kernel<<<ublocks + iblocks, 256, 0, stream>>>(
            z_user, z_item, W1, b1, Pu, Pi, n_user, n_item, ublocks);
        edge_sorted_kernel<<<2048, 256, 0, stream>>>(Pu, Pi, srt, cur, W2, b2, ps, cap);
        permute_kernel<<<1024, 256, 0, stream>>>(ps, inv, out, E);
    } else if (ws_size >= needProj) {
        unsigned short* Pu = (unsigned short*)((char*)d_ws + offPu);
        unsigned short* Pi = (unsigned short*)((char*)d_ws + offPi);
        project_both_kernel<<<ublocks + iblocks, 256, 0, stream>>>(
            z_user, z_item, W1, b1, Pu, Pi, n_user, n_item, ublocks);
        edge_bf16_kernel<<<2048, 256, 0, stream>>>(Pu, Pi, row, col, W2, b2, out, E);
    } else {
        edge_direct_kernel<<<2048, 256, 0, stream>>>(z_user, z_item, row, col, W1, b1, W2, b2, out, E);
    }
}

// Round 7
// 101.148 us; speedup vs baseline: 2.2514x; 1.1217x over previous
//
#include <hip/hip_runtime.h>

#define HH 128
#define BU 8        // user buckets (one per XCD)
#define BI 32       // item sub-buckets
#define NBKT (BU * BI)
#define SCHUNK 2048 // edges per scatter block

typedef __attribute__((ext_vector_type(8))) short bf16x8;
typedef __attribute__((ext_vector_type(4))) float f32x4;
typedef _Float16 h2 __attribute__((ext_vector_type(2)));
typedef unsigned long long u64;

#if __has_builtin(__builtin_amdgcn_fdot2)
#define FDOT2(a, b, c) __builtin_amdgcn_fdot2((a), (b), (c), false)
#else
#define FDOT2(a, b, c) ((c) + (float)(a)[0] * (float)(b)[0] + (float)(a)[1] * (float)(b)[1])
#endif

__device__ inline unsigned short f2bf(float f) {
    unsigned u = __builtin_bit_cast(unsigned, f);
    u += 0x7FFF + ((u >> 16) & 1);
    return (unsigned short)(u >> 16);
}
__device__ inline unsigned short f2h(float f) {
    return __builtin_bit_cast(unsigned short, (_Float16)f);
}

// ================= mega kernel: scatter blocks + projection blocks =================
// blocks [0, scatBlocks): bucket-binning scatter of edges (u32 records + invpos)
// blocks [scatBlocks, +ublocks+iblocks): MFMA projection -> fp16 tables (b1 folded into Pu)
__global__ __launch_bounds__(256) void mega_kernel(
    const float* __restrict__ Zu, const float* __restrict__ Zi,
    const float* __restrict__ W1, const float* __restrict__ b1,
    unsigned short* __restrict__ Pu, unsigned short* __restrict__ Pi,
    const int* __restrict__ row, const int* __restrict__ col,
    unsigned* __restrict__ cursor, unsigned* __restrict__ srt,
    unsigned* __restrict__ invpos,
    int n_user, int n_item, int E, int cap, int scatBlocks, int ublocks)
{
    __shared__ unsigned short sWt[128 * 128];    // 32 KB (aliased by scatter LDS)
    __shared__ unsigned short sOut[64 * 136];    // 17 KB

    const int t = threadIdx.x;

    if ((int)blockIdx.x < scatBlocks) {
        // ---------------- scatter ----------------
        unsigned* lh = (unsigned*)sWt;           // 256
        unsigned* gb = lh + NBKT;                // 256
        unsigned* lc = gb + NBKT;                // 256
        const int base = blockIdx.x * SCHUNK;

        int uu[SCHUNK / 256], ii[SCHUNK / 256];
        lh[t] = 0;
        __syncthreads();
        #pragma unroll
        for (int k = 0; k < SCHUNK / 256; ++k) {
            int e = base + k * 256 + t;
            if (e < E) {
                uu[k] = row[e]; ii[k] = col[e];
                unsigned uc = ((unsigned)uu[k] * BU) / (unsigned)n_user;
                unsigned ic = ((unsigned)ii[k] * BI) / (unsigned)n_item;
                atomicAdd(&lh[uc * BI + ic], 1u);
            }
        }
        __syncthreads();
        gb[t] = lh[t] ? (unsigned)(t * cap) + atomicAdd(&cursor[t], lh[t]) : 0u;
        lc[t] = 0;
        __syncthreads();
        #pragma unroll
        for (int k = 0; k < SCHUNK / 256; ++k) {
            int e = base + k * 256 + t;
            if (e < E) {
                unsigned uc = ((unsigned)uu[k] * BU) / (unsigned)n_user;
                unsigned ic = ((unsigned)ii[k] * BI) / (unsigned)n_item;
                int b = (int)(uc * BI + ic);
                unsigned ucbase = (uc * (unsigned)n_user + 7u) >> 3;
                unsigned r   = atomicAdd(&lc[b], 1u);
                unsigned pos = gb[b] + r;
                srt[pos]  = (((unsigned)uu[k] - ucbase) << 16) | (unsigned)ii[k];
                invpos[e] = pos;
            }
        }
        return;
    }

    // ---------------- projection ----------------
    const int pbid = (int)blockIdx.x - scatBlocks;
    const bool isUser = (pbid < ublocks);
    const float* __restrict__ Z = isUser ? Zu : Zi;
    const float* __restrict__ W = isUser ? W1 : (W1 + HH * HH);
    unsigned short* __restrict__ P = isUser ? Pu : Pi;
    const int nrows  = isUser ? n_user : n_item;
    const int ntiles = (nrows + 63) >> 6;
    const int tbase  = (isUser ? pbid : (pbid - ublocks)) * 2;

    const int wave = t >> 6;
    const int lane = t & 63;
    const int l16  = lane & 15;
    const int lk8  = (lane >> 4) * 8;

    #pragma unroll 4
    for (int i = 0; i < 16; ++i) {
        int idx = t + i * 256;
        int k   = idx >> 5;
        int c4  = (idx & 31) * 4;
        float4 w = *(const float4*)(W + (size_t)k * HH + c4);
        float wv[4] = {w.x, w.y, w.z, w.w};
        #pragma unroll
        for (int j = 0; j < 4; ++j) {
            int c = c4 + j;
            sWt[c * 128 + (((k >> 3) ^ (c & 15)) << 3) + (k & 7)] = f2bf(wv[j]);
        }
    }

    float b1r[8];
    #pragma unroll
    for (int nt = 0; nt < 8; ++nt)
        b1r[nt] = isUser ? b1[nt * 16 + l16] : 0.f;

    __syncthreads();

    #pragma unroll 1
    for (int s = 0; s < 2; ++s) {
        const int tile = tbase + s;
        if (tile >= ntiles) break;
        const int rbase = tile << 6;

        f32x4 acc[8];
        #pragma unroll
        for (int nt = 0; nt < 8; ++nt) acc[nt] = (f32x4)0.f;

        int m = rbase + wave * 16 + l16;
        if (m > nrows - 1) m = nrows - 1;
        const float* Zrow = Z + (size_t)m * HH;

        #pragma unroll
        for (int kk = 0; kk < 4; ++kk) {
            float4 z0 = *(const float4*)(Zrow + kk * 32 + lk8);
            float4 z1 = *(const float4*)(Zrow + kk * 32 + lk8 + 4);
            bf16x8 a;
            a[0] = (short)f2bf(z0.x); a[1] = (short)f2bf(z0.y);
            a[2] = (short)f2bf(z0.z); a[3] = (short)f2bf(z0.w);
            a[4] = (short)f2bf(z1.x); a[5] = (short)f2bf(z1.y);
            a[6] = (short)f2bf(z1.z); a[7] = (short)f2bf(z1.w);

            const int chunkSw = ((kk * 4 + (lane >> 4)) ^ l16) << 3;
            #pragma unroll
            for (int nt = 0; nt < 8; ++nt) {
                int c = nt * 16 + l16;
                bf16x8 b = *(const bf16x8*)(sWt + c * 128 + chunkSw);
                acc[nt] = __builtin_amdgcn_mfma_f32_16x16x32_bf16(a, b, acc[nt], 0, 0, 0);
            }
        }

        __syncthreads();
        #pragma unroll
        for (int nt = 0; nt < 8; ++nt) {
            int colc = nt * 16 + l16;
            #pragma unroll
            for (int r = 0; r < 4; ++r) {
                int orow = wave * 16 + (lane >> 4) * 4 + r;
                sOut[orow * 136 + colc] = f2h(acc[nt][r] + b1r[nt]);   // fp16 table
            }
        }
        __syncthreads();
        #pragma unroll
        for (int i = 0; i < 4; ++i) {
            int idx = t + i * 256;
            int r   = idx >> 4;
            int ch  = idx & 15;
            int grow = rbase + r;
            if (grow < nrows)
                *(uint4*)(P + (size_t)grow * HH + ch * 8) =
                    *(const uint4*)(sOut + r * 136 + ch * 8);
        }
    }
}

// ================= edge kernel: 8 lanes/edge, fp16 packed math =================
__global__ __launch_bounds__(256) void edge_sorted_kernel(
    const unsigned short* __restrict__ Pu, const unsigned short* __restrict__ Pi,
    const unsigned* __restrict__ srt, const unsigned* __restrict__ cursor,
    const float* __restrict__ W2, const float* __restrict__ b2,
    float* __restrict__ psorted, int cap, int n_user)
{
    const int uc     = blockIdx.x & (BU - 1);
    const int jj     = blockIdx.x >> 3;          // 0..255
    const int g      = threadIdx.x >> 3;         // 0..31
    const int lane8  = threadIdx.x & 7;
    const int gg     = jj * 32 + g;              // 0..8191
    const int c0     = lane8 * 16;               // channel base (16 ch = 32B)
    const int ucbase = (int)(((unsigned)uc * (unsigned)n_user + 7u) >> 3);

    h2 w2h[8];
    #pragma unroll
    for (int j = 0; j < 8; ++j) {
        w2h[j][0] = (_Float16)W2[c0 + 2 * j];
        w2h[j][1] = (_Float16)W2[c0 + 2 * j + 1];
    }
    const float b2s = b2[0];
    const h2 hz = {(_Float16)0, (_Float16)0};

    #pragma unroll 1
    for (int ic = 0; ic < BI; ++ic) {
        const int b    = uc * BI + ic;
        const int S    = b * cap;
        const int Tend = S + (int)cursor[b];
        for (int p = S + gg; p < Tend; p += BU * 1024) {  // 8192 groups per uc
            unsigned pk = srt[p];
            int u  = ucbase + (int)(pk >> 16);
            int it = (int)(pk & 0xFFFFu);
            const unsigned short* pur = Pu + (size_t)u  * HH + c0;
            const unsigned short* pir = Pi + (size_t)it * HH + c0;
            uint4 a0 = *(const uint4*)pur;
            uint4 a1 = *(const uint4*)(pur + 8);
            uint4 c0v = *(const uint4*)pir;
            uint4 c1v = *(const uint4*)(pir + 8);
            unsigned aw[8] = {a0.x, a0.y, a0.z, a0.w, a1.x, a1.y, a1.z, a1.w};
            unsigned cw[8] = {c0v.x, c0v.y, c0v.z, c0v.w, c1v.x, c1v.y, c1v.z, c1v.w};
            float acc = 0.f;
            #pragma unroll
            for (int q = 0; q < 8; ++q) {
                h2 s = __builtin_bit_cast(h2, aw[q]) + __builtin_bit_cast(h2, cw[q]);
                s = __builtin_elementwise_max(s, hz);
                acc = FDOT2(s, w2h[q], acc);
            }
            acc += __shfl_xor(acc, 4, 64);
            acc += __shfl_xor(acc, 2, 64);
            acc += __shfl_xor(acc, 1, 64);
            if (lane8 == 0) psorted[p] = acc + b2s;
        }
    }
}

// ================= permutation: out[e] = psorted[invpos[e]] =================
__global__ __launch_bounds__(256) void permute_kernel(
    const float* __restrict__ psorted, const unsigned* __restrict__ invpos,
    float* __restrict__ out, int E)
{
    int i  = blockIdx.x * blockDim.x + threadIdx.x;
    int st = gridDim.x * blockDim.x;
    for (int e = i; e < E; e += st)
        out[e] = psorted[invpos[e]];
}

// ================= fallback: unsorted fp16 gather =================
__global__ __launch_bounds__(256) void edge_fp16_kernel(
    const unsigned short* __restrict__ Pu, const unsigned short* __restrict__ Pi,
    const int* __restrict__ row, const int* __restrict__ col,
    const float* __restrict__ W2, const float* __restrict__ b2,
    float* __restrict__ out, int E)
{
    const int lane8  = threadIdx.x & 7;
    const int gid    = (blockIdx.x * blockDim.x + threadIdx.x) >> 3;
    const int stride = (gridDim.x * blockDim.x) >> 3;
    const int c0     = lane8 * 16;

    h2 w2h[8];
    #pragma unroll
    for (int j = 0; j < 8; ++j) {
        w2h[j][0] = (_Float16)W2[c0 + 2 * j];
        w2h[j][1] = (_Float16)W2[c0 + 2 * j + 1];
    }
    const float b2s = b2[0];
    const h2 hz = {(_Float16)0, (_Float16)0};

    for (int e = gid; e < E; e += stride) {
        int u = row[e], it = col[e];
        const unsigned short* pur = Pu + (size_t)u  * HH + c0;
        const unsigned short* pir = Pi + (size_t)it * HH + c0;
        uint4 a0 = *(const uint4*)pur;
        uint4 a1 = *(const uint4*)(pur + 8);
        uint4 c0v = *(const uint4*)pir;
        uint4 c1v = *(const uint4*)(pir + 8);
        unsigned aw[8] = {a0.x, a0.y, a0.z, a0.w, a1.x, a1.y, a1.z, a1.w};
        unsigned cw[8] = {c0v.x, c0v.y, c0v.z, c0v.w, c1v.x, c1v.y, c1v.z, c1v.w};
        float acc = 0.f;
        #pragma unroll
        for (int q = 0; q < 8; ++q) {
            h2 s = __builtin_bit_cast(h2, aw[q]) + __builtin_bit_cast(h2, cw[q]);
            s = __builtin_elementwise_max(s, hz);
            acc = FDOT2(s, w2h[q], acc);
        }
        acc += __shfl_xor(acc, 4, 64);
        acc += __shfl_xor(acc, 2, 64);
        acc += __shfl_xor(acc, 1, 64);
        if (lane8 == 0) out[e] = acc + b2s;
    }
}

// ================= fallback (no workspace): direct per-edge fp32 compute =================
__global__ __launch_bounds__(256) void edge_direct_kernel(
    const float* __restrict__ zu, const float* __restrict__ zi,
    const int* __restrict__ row, const int* __restrict__ col,
    const float* __restrict__ W1, const float* __restrict__ b1,
    const float* __restrict__ W2, const float* __restrict__ b2,
    float* __restrict__ out, int E)
{
    const int lane   = threadIdx.x & 31;
    const int gid    = (blockIdx.x * blockDim.x + threadIdx.x) >> 5;
    const int stride = (gridDim.x * blockDim.x) >> 5;
    const int c0     = lane * 4;

    const float4 b1v = *(const float4*)(b1 + c0);
    const float4 w2v = *(const float4*)(W2 + c0);
    const float  b2s = b2[0];

    for (int e = gid; e < E; e += stride) {
        int u  = row[e];
        int it = col[e];
        const float* zur = zu + (size_t)u  * HH;
        const float* zir = zi + (size_t)it * HH;
        float4 acc = b1v;
        for (int k = 0; k < HH; ++k) {
            float  zk = zur[k];
            float4 w  = *(const float4*)(W1 + (size_t)k * HH + c0);
            acc.x = fmaf(zk, w.x, acc.x);
            acc.y = fmaf(zk, w.y, acc.y);
            acc.z = fmaf(zk, w.z, acc.z);
            acc.w = fmaf(zk, w.w, acc.w);
        }
        for (int k = 0; k < HH; ++k) {
            float  zk = zir[k];
            float4 w  = *(const float4*)(W1 + (size_t)(HH + k) * HH + c0);
            acc.x = fmaf(zk, w.x, acc.x);
            acc.y = fmaf(zk, w.y, acc.y);
            acc.z = fmaf(zk, w.z, acc.z);
            acc.w = fmaf(zk, w.w, acc.w);
        }
        float p = fmaxf(acc.x, 0.f) * w2v.x;
        p = fmaf(fmaxf(acc.y, 0.f), w2v.y, p);
        p = fmaf(fmaxf(acc.z, 0.f), w2v.z, p);
        p = fmaf(fmaxf(acc.w, 0.f), w2v.w, p);
        #pragma unroll
        for (int m = 16; m >= 1; m >>= 1)
            p += __shfl_xor(p, m, 64);
        if (lane == 0) out[e] = p + b2s;
    }
}

static inline size_t align256(size_t x) { return (x + 255) & ~(size_t)255; }

extern "C" void kernel_launch(void* const* d_in, const int* in_sizes, int n_in,
                              void* d_out, int out_size, void* d_ws, size_t ws_size,
                              hipStream_t stream)
{
    const float* z_user = (const float*)d_in[0];
    const float* z_item = (const float*)d_in[1];
    const int*   row    = (const int*)d_in[2];
    const int*   col    = (const int*)d_in[3];
    const float* W1     = (const float*)d_in[4];
    const float* b1     = (const float*)d_in[5];
    const float* W2     = (const float*)d_in[6];
    const float* b2     = (const float*)d_in[7];
    float*       out    = (float*)d_out;

    const int n_user = in_sizes[0] / HH;
    const int n_item = in_sizes[1] / HH;
    const int E      = in_sizes[2];

    const int capBase = (E + NBKT - 1) / NBKT;
    const int cap     = capBase + capBase / 4 + 64;
    const size_t padded = (size_t)cap * NBKT;

    // workspace layout
    const size_t offPu  = 0;
    const size_t offPi  = align256(offPu  + (size_t)n_user * HH * 2);
    const size_t offSrt = align256(offPi  + (size_t)n_item * HH * 2);
    const size_t offPs  = align256(offSrt + padded * 4);
    const size_t offInv = align256(offPs  + padded * 4);
    const size_t offCur = align256(offInv + (size_t)E * 4);
    const size_t needSort = align256(offCur + NBKT * 4);
    const size_t needProj = align256(offPi + (size_t)n_item * HH * 2);

    const bool sortable = (n_user >= BU) && (n_item >= BI) &&
                          (n_item < 65536) && (n_user / BU + 1 < 65536) &&
                          (n_user <= (1 << 17)) && (ws_size >= needSort);

    const int utiles  = (n_user + 63) >> 6;
    const int itiles  = (n_item + 63) >> 6;
    const int ublocks = (utiles + 1) >> 1;
    const int iblocks = (itiles + 1) >> 1;
    const int scatBlocks = (E + SCHUNK - 1) / SCHUNK;

    if (sortable) {
        unsigned short* Pu  = (unsigned short*)((char*)d_ws + offPu);
        unsigned short* Pi  = (unsigned short*)((char*)d_ws + offPi);
        unsigned*       srt = (unsigned*)((char*)d_ws + offSrt);
        float*          ps  = (float*)((char*)d_ws + offPs);
        unsigned*       inv = (unsigned*)((char*)d_ws + offInv);
        unsigned*       cur = (unsigned*)((char*)d_ws + offCur);

        hipMemsetAsync(cur, 0, NBKT * 4, stream);
        mega_kernel<<<scatBlocks + ublocks + iblocks, 256, 0, stream>>>(
            z_user, z_item, W1, b1, Pu, Pi, row, col, cur, srt, inv,
            n_user, n_item, E, cap, scatBlocks, ublocks);
        edge_sorted_kernel<<<2048, 256, 0, stream>>>(Pu, Pi, srt, cur, W2, b2, ps, cap, n_user);
        permute_kernel<<<1024, 256, 0, stream>>>(ps, inv, out, E);
    } else if (ws_size >= needProj) {
        unsigned short* Pu = (unsigned short*)((char*)d_ws + offPu);
        unsigned short* Pi = (unsigned short*)((char*)d_ws + offPi);
        mega_kernel<<<ublocks + iblocks, 256, 0, stream>>>(
            z_user, z_item, W1, b1, Pu, Pi, row, col,
            (unsigned*)nullptr, (unsigned*)nullptr, (unsigned*)nullptr,
            n_user, n_item, E, cap, 0, ublocks);
        edge_fp16_kernel<<<2048, 256, 0, stream>>>(Pu, Pi, row, col, W2, b2, out, E);
    } else {
        edge_direct_kernel<<<2048, 256, 0, stream>>>(z_user, z_item, row, col, W1, b1, W2, b2, out, E);
    }
}